// Round 1
// baseline (694.919 us; speedup 1.0000x reference)
//
#include <hip/hip_runtime.h>
#include <math.h>

typedef float f4 __attribute__((ext_vector_type(4)));

#define NB 1024
#define NR 10
#define NL 512
#define NM (NB*NR)      // 10240 rows
#define NK (2*NL)       // 1024  K-dim

// ---------------- workspace zero-init (ws is poisoned 0xAA each call) ----------
__global__ __launch_bounds__(256) void k_init(float* __restrict__ t) {
    int i = blockIdx.x*256 + threadIdx.x;
    if (i < 2*NM) t[i] = 0.0f;
}

// ---------------- v_h = W1[:L]@W2, v_q = W1[L:]@W2, c = b1.W2 + b2 -------------
__global__ __launch_bounds__(256) void k_vcalc(const float* __restrict__ W1,
                                               const float* __restrict__ b1,
                                               const float* __restrict__ W2,
                                               const float* __restrict__ b2,
                                               float* __restrict__ vh,
                                               float* __restrict__ vq,
                                               float* __restrict__ cc) {
    int tid = blockIdx.x*256 + threadIdx.x;
    if (tid < 2*NL) {
        const float* row = W1 + (size_t)tid*NL;
        float s = 0.0f;
        #pragma unroll 4
        for (int k = 0; k < NL; ++k) s = fmaf(row[k], W2[k], s);
        if (tid < NL) vh[tid] = s; else vq[tid-NL] = s;
    } else if (tid == 2*NL) {
        float s = 0.0f;
        for (int k = 0; k < NL; ++k) s = fmaf(b1[k], W2[k], s);
        cc[0] = s + b2[0];
    }
}

// ---------------- fused gated-trans + projection to per-row scalar -------------
// t[row] += sum_c v[c] * tanh(X.Wy + by)[row,c] * sigmoid(X.Wg + bg)[row,c]
// block: 64 rows x 64 cols tile, both branches share the A tile.
__global__ __launch_bounds__(256) void k_embed(const float* __restrict__ X,
    const float* __restrict__ Wy, const float* __restrict__ by,
    const float* __restrict__ Wg, const float* __restrict__ bg,
    const float* __restrict__ v, float* __restrict__ tout)
{
    __shared__ float As[32][68];   // [k][row], stride 68 keeps f4 reads 16B-aligned
    __shared__ float Bys[32][64];  // [k][col]
    __shared__ float Bgs[32][64];

    const int tid  = threadIdx.x;
    const int row0 = blockIdx.x * 64;
    const int c0   = blockIdx.y * 64;
    const int tx = tid & 15, ty = tid >> 4;   // 16 col-groups x 16 row-groups

    float accy[4][4] = {};
    float accg[4][4] = {};

    const int arow = tid >> 3;        // 0..31
    const int ak   = (tid & 7) << 2;  // 0,4,...,28
    const int bk   = tid >> 4;        // 0..15
    const int bc   = (tid & 15) << 2; // 0..60

    const float* Xp0 = X + (size_t)(row0 + arow)*NK + ak;
    const float* Xp1 = Xp0 + (size_t)32*NK;

    for (int k0 = 0; k0 < NK; k0 += 32) {
        f4 a0 = *(const f4*)(Xp0 + k0);
        f4 a1 = *(const f4*)(Xp1 + k0);
        f4 y0 = *(const f4*)&Wy[(size_t)(k0+bk   )*NL + c0 + bc];
        f4 y1 = *(const f4*)&Wy[(size_t)(k0+bk+16)*NL + c0 + bc];
        f4 g0 = *(const f4*)&Wg[(size_t)(k0+bk   )*NL + c0 + bc];
        f4 g1 = *(const f4*)&Wg[(size_t)(k0+bk+16)*NL + c0 + bc];
        #pragma unroll
        for (int j = 0; j < 4; ++j) {
            As[ak+j][arow]      = a0[j];
            As[ak+j][arow + 32] = a1[j];
        }
        *(f4*)&Bys[bk   ][bc] = y0;
        *(f4*)&Bys[bk+16][bc] = y1;
        *(f4*)&Bgs[bk   ][bc] = g0;
        *(f4*)&Bgs[bk+16][bc] = g1;
        __syncthreads();
        #pragma unroll
        for (int kk = 0; kk < 32; ++kk) {
            f4 a   = *(const f4*)&As [kk][ty<<2];
            f4 byv = *(const f4*)&Bys[kk][tx<<2];
            f4 bgv = *(const f4*)&Bgs[kk][tx<<2];
            #pragma unroll
            for (int rr = 0; rr < 4; ++rr)
                #pragma unroll
                for (int cc2 = 0; cc2 < 4; ++cc2) {
                    accy[rr][cc2] = fmaf(a[rr], byv[cc2], accy[rr][cc2]);
                    accg[rr][cc2] = fmaf(a[rr], bgv[cc2], accg[rr][cc2]);
                }
        }
        __syncthreads();
    }

    // epilogue: nonlinearity + weighted column-reduce
    float rowsum[4] = {0.f, 0.f, 0.f, 0.f};
    #pragma unroll
    for (int rr = 0; rr < 4; ++rr)
        #pragma unroll
        for (int cc2 = 0; cc2 < 4; ++cc2) {
            int c = c0 + (tx<<2) + cc2;
            float xy = accy[rr][cc2] + by[c];
            float xg = accg[rr][cc2] + bg[c];
            float hv = tanhf(xy) * (1.0f / (1.0f + expf(-xg)));
            rowsum[rr] += v[c] * hv;
        }

    float* red = &As[0][0];   // reuse LDS (safe: final loop iter ended on sync)
    #pragma unroll
    for (int rr = 0; rr < 4; ++rr) red[(ty*4 + rr)*16 + tx] = rowsum[rr];
    __syncthreads();
    if (tid < 64) {
        float s = 0.0f;
        #pragma unroll
        for (int t2 = 0; t2 < 16; ++t2) s += red[tid*16 + t2];
        atomicAdd(&tout[row0 + tid], s);
    }
}

// ---------------- logits -> masked Gumbel argmax -> one-hot --------------------
__global__ __launch_bounds__(256) void k_final(const float* __restrict__ th,
    const float* __restrict__ tq, const float* __restrict__ cc,
    const float* __restrict__ noise, const float* __restrict__ Wa,
    const float* __restrict__ ba, float* __restrict__ out)
{
    int idx = blockIdx.x*256 + threadIdx.x;   // = b*NR + i
    if (idx >= NM) return;
    int b = idx / NR, i = idx % NR;
    float wa0 = Wa[0], wa1 = Wa[1], bav = ba[0], c = cc[0];
    float ti = tq[idx];
    const float EPS = 1e-10f;
    float best = -3.0e38f; int am = 0;
    for (int j = 0; j < NR; ++j) {
        float z;
        if (j <= i) {
            float n = noise[idx*NR + j];
            float g = -logf(EPS - logf(n + EPS));          // Gumbel
            float score = ti + th[b*NR + j] + c;
            z = score*wa0 + (float)(i - j + 1)*wa1 + bav + g;
        } else {
            z = -1.0e9f;
        }
        if (z > best) { best = z; am = j; }                // ties -> first (np.argmax)
    }
    #pragma unroll
    for (int j = 0; j < NR; ++j) out[idx*NR + j] = (j == am) ? 1.0f : 0.0f;
}

extern "C" void kernel_launch(void* const* d_in, const int* in_sizes, int n_in,
                              void* d_out, int out_size, void* d_ws, size_t ws_size,
                              hipStream_t stream) {
    (void)in_sizes; (void)n_in; (void)out_size; (void)ws_size;
    const float* hist  = (const float*)d_in[0];
    const float* ques  = (const float*)d_in[1];
    const float* noise = (const float*)d_in[2];
    const float* Wy_h  = (const float*)d_in[3];
    const float* by_h  = (const float*)d_in[4];
    const float* Wg_h  = (const float*)d_in[5];
    const float* bg_h  = (const float*)d_in[6];
    const float* Wy_q  = (const float*)d_in[7];
    const float* by_q  = (const float*)d_in[8];
    const float* Wg_q  = (const float*)d_in[9];
    const float* bg_q  = (const float*)d_in[10];
    const float* W1    = (const float*)d_in[11];
    const float* b1    = (const float*)d_in[12];
    const float* W2    = (const float*)d_in[13];
    const float* b2    = (const float*)d_in[14];
    const float* Wa    = (const float*)d_in[15];
    const float* ba    = (const float*)d_in[16];
    float* out = (float*)d_out;

    float* ws   = (float*)d_ws;
    float* t_h  = ws;                 // [10240]
    float* t_q  = ws + NM;            // [10240]
    float* v_h  = ws + 2*NM;          // [512]
    float* v_q  = v_h + NL;           // [512]
    float* cconst = v_q + NL;         // [1]

    k_init<<<(2*NM + 255)/256, 256, 0, stream>>>(t_h);
    k_vcalc<<<5, 256, 0, stream>>>(W1, b1, W2, b2, v_h, v_q, cconst);
    dim3 g(NM/64, NL/64);
    k_embed<<<g, 256, 0, stream>>>(hist, Wy_h, by_h, Wg_h, bg_h, v_h, t_h);
    k_embed<<<g, 256, 0, stream>>>(ques, Wy_q, by_q, Wg_q, bg_q, v_q, t_q);
    k_final<<<(NM + 255)/256, 256, 0, stream>>>(t_h, t_q, cconst, noise, Wa, ba, out);
}

// Round 2
// 319.665 us; speedup vs baseline: 2.1739x; 2.1739x over previous
//
#include <hip/hip_runtime.h>
#include <math.h>

typedef float f4 __attribute__((ext_vector_type(4)));
typedef float f32x4 __attribute__((ext_vector_type(4)));
typedef _Float16 h4 __attribute__((ext_vector_type(4)));
typedef _Float16 h8 __attribute__((ext_vector_type(8)));

#define NB 1024
#define NR 10
#define NL 512
#define NM (NB*NR)      // 10240 rows
#define NK (2*NL)       // 1024  K-dim

#define BIMG_OFF   131072ull      // byte offset of weight images inside ws
#define BIMG_EMBED 4194304ull     // bytes per embed image (2 branches x 2 splits x 512x1024 f16)
#define WS_NEED    (BIMG_OFF + 2ull*BIMG_EMBED)

#define SCALE_A 16.0f
#define SCALE_B 512.0f
#define INV_SCALE (1.0f/8192.0f)

// ---------------- workspace zero-init --------------------------------------
__global__ __launch_bounds__(256) void k_init(float* __restrict__ t) {
    int i = blockIdx.x*256 + threadIdx.x;
    if (i < 2*NM) t[i] = 0.0f;
}

// ---------------- v_h = W1[:L]@W2, v_q = W1[L:]@W2, c = b1.W2 + b2 ----------
__global__ __launch_bounds__(256) void k_vcalc(const float* __restrict__ W1,
                                               const float* __restrict__ b1,
                                               const float* __restrict__ W2,
                                               const float* __restrict__ b2,
                                               float* __restrict__ vh,
                                               float* __restrict__ vq,
                                               float* __restrict__ cc) {
    int tid = blockIdx.x*256 + threadIdx.x;
    if (tid < 2*NL) {
        const float* row = W1 + (size_t)tid*NL;
        float s = 0.0f;
        #pragma unroll 4
        for (int k = 0; k < NL; ++k) s = fmaf(row[k], W2[k], s);
        if (tid < NL) vh[tid] = s; else vq[tid-NL] = s;
    } else if (tid == 2*NL) {
        float s = 0.0f;
        for (int k = 0; k < NL; ++k) s = fmaf(b1[k], W2[k], s);
        cc[0] = s + b2[0];
    }
}

// ---------------- weight pre-split: f32 -> scaled f16 hi/lo fragment image --
// Image layout per embed: [nt(8)][ks(32)][s(2)][nf(8)][lane(64)][e(8)] f16
// where nf 0..3 = Wy cols (nt*64 + nf*16 + (l&15)), nf 4..7 = Wg cols,
// k = ks*32 + (l>>4)*8 + e.  This is exactly the LDS tile image.
__global__ __launch_bounds__(256) void k_wsplit(const float* __restrict__ Wy_h,
    const float* __restrict__ Wg_h, const float* __restrict__ Wy_q,
    const float* __restrict__ Wg_q, char* __restrict__ Bimg)
{
    const int nh = blockIdx.x;      // 0..7  (64-col tile)
    const int ks = blockIdx.y;      // 0..31 (32-k step)
    const int mi = blockIdx.z;      // 0..3  matrix select
    const float* W = (mi==0) ? Wy_h : (mi==1) ? Wg_h : (mi==2) ? Wy_q : Wg_q;
    const int emb = mi >> 1, nfb = (mi & 1) * 4;
    __shared__ float Ws[32][68];
    const int t = threadIdx.x;
    const int kl = t >> 4, nl4 = (t & 15) * 4;
    #pragma unroll
    for (int i = 0; i < 2; ++i) {
        f4 wv = *(const f4*)(W + (size_t)(ks*32 + kl + 16*i)*NL + nh*64 + nl4);
        *(f4*)&Ws[kl + 16*i][nl4] = wv;
    }
    __syncthreads();
    const int kg = t >> 6, nl = t & 63;
    h8 hi, lo;
    #pragma unroll
    for (int e8 = 0; e8 < 8; ++e8) {
        float x = Ws[kg*8 + e8][nl] * SCALE_B;
        _Float16 h = (_Float16)x;
        hi[e8] = h;
        lo[e8] = (_Float16)(x - (float)h);
    }
    const int nf  = nfb + (nl >> 4);
    const int l16 = (nl & 15) + 16*kg;
    char* p = Bimg + (size_t)emb*BIMG_EMBED
            + ((size_t)(nh*32 + ks)*2)*8192 + nf*1024 + l16*16;
    *(h8*)p = hi;
    *(h8*)(p + 8192) = lo;
}

// ---------------- fused gated-trans via split-f16 MFMA ----------------------
// Block tile: 128 rows x (64 y-cols + 64 g-cols).  4 waves = 2(row) x 2(col).
// acc[m][0..1] = y fragments, acc[m][2..3] = g fragments of the SAME cols.
__global__ __launch_bounds__(256, 2) void k_embed_mfma(
    const float* __restrict__ hist, const float* __restrict__ ques,
    const char* __restrict__ Bimg,
    const float* __restrict__ by_h, const float* __restrict__ bg_h,
    const float* __restrict__ by_q, const float* __restrict__ bg_q,
    const float* __restrict__ vv,   // v_h at +0, v_q at +NL
    float* __restrict__ tout)       // t_h at +0, t_q at +NM
{
    const int z = blockIdx.z;
    const float* X  = z ? ques : hist;
    const float* by = z ? by_q : by_h;
    const float* bg = z ? bg_q : bg_h;
    const float* v  = vv + z*NL;
    float* tptr = tout + (size_t)z*NM;
    const int nt = blockIdx.y;
    const char* Bt0 = Bimg + (size_t)z*BIMG_EMBED + (size_t)nt*32*16384;
    const int row0 = blockIdx.x * 128;

    __shared__ uint4 smem[2048];          // 32 KB: A [0,16K), B [16K,32K)
    char* sA = (char*)smem;
    char* sB = sA + 16384;
    uint4* sB4 = smem + 1024;

    const int t = threadIdx.x;
    const int l = t & 63, w = t >> 6;
    const int wr = w >> 1, wc = w & 1;

    // A staging mapping: thread covers rows (t>>3)+32i, k-chunk (t&7)*4
    const int arow = t >> 3;
    const int ak4  = (t & 7) << 2;
    const int akg  = (t & 7) >> 1;
    const int ae0  = (t & 1) << 2;
    const float* Xp = X + (size_t)(row0 + arow)*NK + ak4;
    const int awb = ((arow >> 4) * 1024) + (((arow & 15) + 16*akg) * 16) + ae0*2;

    f32x4 acc[4][4];
    #pragma unroll
    for (int m = 0; m < 4; ++m)
      #pragma unroll
      for (int n = 0; n < 4; ++n) { f32x4 zz = {0.f,0.f,0.f,0.f}; acc[m][n] = zz; }

    for (int ks = 0; ks < 32; ++ks) {
        const int k0 = ks << 5;
        // ---- stage A: load f32, split to scaled f16 hi/lo, write frag-linear
        #pragma unroll
        for (int i = 0; i < 4; ++i) {
            f4 a = *(const f4*)(Xp + k0 + (size_t)i*32*NK);
            h4 hi, lo;
            #pragma unroll
            for (int j = 0; j < 4; ++j) {
                float xs = a[j] * SCALE_A;
                _Float16 h = (_Float16)xs;
                hi[j] = h;
                lo[j] = (_Float16)(xs - (float)h);
            }
            *(h4*)(sA +        awb + i*2048) = hi;
            *(h4*)(sA + 8192 + awb + i*2048) = lo;
        }
        // ---- stage B: straight copy of pre-split fragment image (16 KB)
        const uint4* bt = (const uint4*)(Bt0 + (size_t)ks*16384);
        #pragma unroll
        for (int j = 0; j < 4; ++j) sB4[t + 256*j] = bt[t + 256*j];
        __syncthreads();
        // ---- fragment loads (lane-linear, conflict-free)
        h8 av[4][2], bv[4][2];
        #pragma unroll
        for (int m = 0; m < 4; ++m)
          #pragma unroll
          for (int s = 0; s < 2; ++s)
            av[m][s] = *(const h8*)(sA + s*8192 + (wr*4 + m)*1024 + l*16);
        #pragma unroll
        for (int fn = 0; fn < 4; ++fn) {
            const int nf = (fn < 2) ? (wc*2 + fn) : (4 + wc*2 + (fn - 2));
            #pragma unroll
            for (int s = 0; s < 2; ++s)
                bv[fn][s] = *(const h8*)(sB + s*8192 + nf*1024 + l*16);
        }
        // ---- 48 MFMAs: hi*hi + hi*lo + lo*hi
        #pragma unroll
        for (int m = 0; m < 4; ++m)
          #pragma unroll
          for (int fn = 0; fn < 4; ++fn) {
            acc[m][fn] = __builtin_amdgcn_mfma_f32_16x16x32_f16(av[m][0], bv[fn][0], acc[m][fn], 0, 0, 0);
            acc[m][fn] = __builtin_amdgcn_mfma_f32_16x16x32_f16(av[m][0], bv[fn][1], acc[m][fn], 0, 0, 0);
            acc[m][fn] = __builtin_amdgcn_mfma_f32_16x16x32_f16(av[m][1], bv[fn][0], acc[m][fn], 0, 0, 0);
          }
        __syncthreads();
    }

    // ---- epilogue: unscale, bias, tanh*sigmoid, dot v, row-reduce, atomic
    const int coll = l & 15, rg = l >> 4;
    #pragma unroll
    for (int m = 0; m < 4; ++m) {
      #pragma unroll
      for (int r = 0; r < 4; ++r) {
        float ps = 0.0f;
        #pragma unroll
        for (int n = 0; n < 2; ++n) {
            const int c = nt*64 + wc*32 + n*16 + coll;
            float y = acc[m][n  ][r]*INV_SCALE + by[c];
            float g = acc[m][n+2][r]*INV_SCALE + bg[c];
            ps += v[c] * (tanhf(y) * (1.0f/(1.0f + expf(-g))));
        }
        ps += __shfl_xor(ps, 1);
        ps += __shfl_xor(ps, 2);
        ps += __shfl_xor(ps, 4);
        ps += __shfl_xor(ps, 8);
        if (coll == 0)
            atomicAdd(&tptr[row0 + wr*64 + m*16 + rg*4 + r], ps);
      }
    }
}

// ---------------- fallback f32 path (verified round 1) ----------------------
__global__ __launch_bounds__(256) void k_embed(const float* __restrict__ X,
    const float* __restrict__ Wy, const float* __restrict__ by,
    const float* __restrict__ Wg, const float* __restrict__ bg,
    const float* __restrict__ v, float* __restrict__ tout)
{
    __shared__ float As[32][68];
    __shared__ float Bys[32][64];
    __shared__ float Bgs[32][64];
    const int tid  = threadIdx.x;
    const int row0 = blockIdx.x * 64;
    const int c0   = blockIdx.y * 64;
    const int tx = tid & 15, ty = tid >> 4;
    float accy[4][4] = {};
    float accg[4][4] = {};
    const int arow = tid >> 3;
    const int ak   = (tid & 7) << 2;
    const int bk   = tid >> 4;
    const int bc   = (tid & 15) << 2;
    const float* Xp0 = X + (size_t)(row0 + arow)*NK + ak;
    const float* Xp1 = Xp0 + (size_t)32*NK;
    for (int k0 = 0; k0 < NK; k0 += 32) {
        f4 a0 = *(const f4*)(Xp0 + k0);
        f4 a1 = *(const f4*)(Xp1 + k0);
        f4 y0 = *(const f4*)&Wy[(size_t)(k0+bk   )*NL + c0 + bc];
        f4 y1 = *(const f4*)&Wy[(size_t)(k0+bk+16)*NL + c0 + bc];
        f4 g0 = *(const f4*)&Wg[(size_t)(k0+bk   )*NL + c0 + bc];
        f4 g1 = *(const f4*)&Wg[(size_t)(k0+bk+16)*NL + c0 + bc];
        #pragma unroll
        for (int j = 0; j < 4; ++j) {
            As[ak+j][arow]      = a0[j];
            As[ak+j][arow + 32] = a1[j];
        }
        *(f4*)&Bys[bk   ][bc] = y0;
        *(f4*)&Bys[bk+16][bc] = y1;
        *(f4*)&Bgs[bk   ][bc] = g0;
        *(f4*)&Bgs[bk+16][bc] = g1;
        __syncthreads();
        #pragma unroll
        for (int kk = 0; kk < 32; ++kk) {
            f4 a   = *(const f4*)&As [kk][ty<<2];
            f4 byv = *(const f4*)&Bys[kk][tx<<2];
            f4 bgv = *(const f4*)&Bgs[kk][tx<<2];
            #pragma unroll
            for (int rr = 0; rr < 4; ++rr)
                #pragma unroll
                for (int cc2 = 0; cc2 < 4; ++cc2) {
                    accy[rr][cc2] = fmaf(a[rr], byv[cc2], accy[rr][cc2]);
                    accg[rr][cc2] = fmaf(a[rr], bgv[cc2], accg[rr][cc2]);
                }
        }
        __syncthreads();
    }
    float rowsum[4] = {0.f, 0.f, 0.f, 0.f};
    #pragma unroll
    for (int rr = 0; rr < 4; ++rr)
        #pragma unroll
        for (int cc2 = 0; cc2 < 4; ++cc2) {
            int c = c0 + (tx<<2) + cc2;
            float xy = accy[rr][cc2] + by[c];
            float xg = accg[rr][cc2] + bg[c];
            float hv = tanhf(xy) * (1.0f / (1.0f + expf(-xg)));
            rowsum[rr] += v[c] * hv;
        }
    float* red = &As[0][0];
    #pragma unroll
    for (int rr = 0; rr < 4; ++rr) red[(ty*4 + rr)*16 + tx] = rowsum[rr];
    __syncthreads();
    if (tid < 64) {
        float s = 0.0f;
        #pragma unroll
        for (int t2 = 0; t2 < 16; ++t2) s += red[tid*16 + t2];
        atomicAdd(&tout[row0 + tid], s);
    }
}

// ---------------- logits -> masked Gumbel argmax -> one-hot -----------------
__global__ __launch_bounds__(256) void k_final(const float* __restrict__ th,
    const float* __restrict__ tq, const float* __restrict__ cc,
    const float* __restrict__ noise, const float* __restrict__ Wa,
    const float* __restrict__ ba, float* __restrict__ out)
{
    int idx = blockIdx.x*256 + threadIdx.x;   // = b*NR + i
    if (idx >= NM) return;
    int b = idx / NR, i = idx % NR;
    float wa0 = Wa[0], wa1 = Wa[1], bav = ba[0], c = cc[0];
    float ti = tq[idx];
    const float EPS = 1e-10f;
    float best = -3.0e38f; int am = 0;
    for (int j = 0; j < NR; ++j) {
        float zz;
        if (j <= i) {
            float n = noise[idx*NR + j];
            float g = -logf(EPS - logf(n + EPS));
            float score = ti + th[b*NR + j] + c;
            zz = score*wa0 + (float)(i - j + 1)*wa1 + bav + g;
        } else {
            zz = -1.0e9f;
        }
        if (zz > best) { best = zz; am = j; }
    }
    #pragma unroll
    for (int j = 0; j < NR; ++j) out[idx*NR + j] = (j == am) ? 1.0f : 0.0f;
}

extern "C" void kernel_launch(void* const* d_in, const int* in_sizes, int n_in,
                              void* d_out, int out_size, void* d_ws, size_t ws_size,
                              hipStream_t stream) {
    (void)in_sizes; (void)n_in; (void)out_size;
    const float* hist  = (const float*)d_in[0];
    const float* ques  = (const float*)d_in[1];
    const float* noise = (const float*)d_in[2];
    const float* Wy_h  = (const float*)d_in[3];
    const float* by_h  = (const float*)d_in[4];
    const float* Wg_h  = (const float*)d_in[5];
    const float* bg_h  = (const float*)d_in[6];
    const float* Wy_q  = (const float*)d_in[7];
    const float* by_q  = (const float*)d_in[8];
    const float* Wg_q  = (const float*)d_in[9];
    const float* bg_q  = (const float*)d_in[10];
    const float* W1    = (const float*)d_in[11];
    const float* b1    = (const float*)d_in[12];
    const float* W2    = (const float*)d_in[13];
    const float* b2    = (const float*)d_in[14];
    const float* Wa    = (const float*)d_in[15];
    const float* ba    = (const float*)d_in[16];
    float* out = (float*)d_out;

    float* ws     = (float*)d_ws;
    float* t_h    = ws;                 // [10240]
    float* t_q    = ws + NM;            // [10240]
    float* v_h    = ws + 2*NM;          // [512]
    float* v_q    = v_h + NL;           // [512]
    float* cconst = v_q + NL;           // [1]

    k_init<<<(2*NM + 255)/256, 256, 0, stream>>>(t_h);
    k_vcalc<<<5, 256, 0, stream>>>(W1, b1, W2, b2, v_h, v_q, cconst);

    if (ws_size >= WS_NEED) {
        char* Bimg = (char*)d_ws + BIMG_OFF;
        k_wsplit<<<dim3(8, 32, 4), 256, 0, stream>>>(Wy_h, Wg_h, Wy_q, Wg_q, Bimg);
        k_embed_mfma<<<dim3(80, 8, 2), 256, 0, stream>>>(hist, ques, Bimg,
            by_h, bg_h, by_q, bg_q, v_h, t_h);
    } else {
        dim3 g(NM/64, NL/64);
        k_embed<<<g, 256, 0, stream>>>(hist, Wy_h, by_h, Wg_h, bg_h, v_h, t_h);
        k_embed<<<g, 256, 0, stream>>>(ques, Wy_q, by_q, Wg_q, bg_q, v_q, t_q);
    }
    k_final<<<(NM + 255)/256, 256, 0, stream>>>(t_h, t_q, cconst, noise, Wa, ba, out);
}

// Round 3
// 314.387 us; speedup vs baseline: 2.2104x; 1.0168x over previous
//
#include <hip/hip_runtime.h>
#include <math.h>

typedef float f4 __attribute__((ext_vector_type(4)));
typedef float f32x4 __attribute__((ext_vector_type(4)));
typedef _Float16 h4 __attribute__((ext_vector_type(4)));
typedef _Float16 h8 __attribute__((ext_vector_type(8)));

#define NB 1024
#define NR 10
#define NL 512
#define NM (NB*NR)      // 10240 rows
#define NK (2*NL)       // 1024  K-dim

#define BIMG_OFF   131072ull
#define BIMG_EMBED 4194304ull                       // 4 MB per embed (B image)
#define AIMG_OFF   (BIMG_OFF + 2ull*BIMG_EMBED)
#define AIMG_EMBED (80ull*32ull*16384ull)           // 40 MB per embed (A image)
#define WS_NEED    (BIMG_OFF + 2ull*BIMG_EMBED)     // ~8.5 MB  (middle path)
#define WS_NEED2   (AIMG_OFF + 2ull*AIMG_EMBED)     // ~92.4 MB (full path)

#define SCALE_A 16.0f
#define SCALE_B 512.0f
#define INV_SCALE (1.0f/8192.0f)

// async global -> LDS, 16B per lane (dest = wave-uniform base + lane*16)
__device__ __forceinline__ void gl_lds16(const void* g, void* s) {
    __builtin_amdgcn_global_load_lds(
        (const __attribute__((address_space(1))) unsigned int*)g,
        (__attribute__((address_space(3))) unsigned int*)s, 16, 0, 0);
}

// ---------------- v_h = W1[:L]@W2, v_q = W1[L:]@W2, c = b1.W2 + b2 ----------
// one block per output element; coalesced row read + wave/LDS reduce
__global__ __launch_bounds__(256) void k_vcalc2(const float* __restrict__ W1,
    const float* __restrict__ b1, const float* __restrict__ W2,
    const float* __restrict__ b2, float* __restrict__ vh,
    float* __restrict__ vq, float* __restrict__ cc)
{
    const int o = blockIdx.x;                 // 0..1024
    const float* row = (o < 1024) ? (W1 + (size_t)o*NL) : b1;
    const int t = threadIdx.x;
    float s = fmaf(row[t], W2[t], row[t+256]*W2[t+256]);
    #pragma unroll
    for (int d = 1; d < 64; d <<= 1) s += __shfl_xor(s, d);
    __shared__ float red[4];
    if ((t & 63) == 0) red[t >> 6] = s;
    __syncthreads();
    if (t == 0) {
        float tot = red[0] + red[1] + red[2] + red[3];
        if (o < 512) vh[o] = tot;
        else if (o < 1024) vq[o-512] = tot;
        else cc[0] = tot + b2[0];
    }
}

// ---------------- weight pre-split: f32 -> scaled f16 hi/lo fragment image --
// per embed: [nt(8)][ks(32)][s(2)][nf(8)][lane(64)][e(8)] f16
__global__ __launch_bounds__(256) void k_wsplit(const float* __restrict__ Wy_h,
    const float* __restrict__ Wg_h, const float* __restrict__ Wy_q,
    const float* __restrict__ Wg_q, char* __restrict__ Bimg)
{
    const int nh = blockIdx.x;      // 0..7
    const int ks = blockIdx.y;      // 0..31
    const int mi = blockIdx.z;      // 0..3
    const float* W = (mi==0) ? Wy_h : (mi==1) ? Wg_h : (mi==2) ? Wy_q : Wg_q;
    const int emb = mi >> 1, nfb = (mi & 1) * 4;
    __shared__ float Ws[32][68];
    const int t = threadIdx.x;
    const int kl = t >> 4, nl4 = (t & 15) * 4;
    #pragma unroll
    for (int i = 0; i < 2; ++i) {
        f4 wv = *(const f4*)(W + (size_t)(ks*32 + kl + 16*i)*NL + nh*64 + nl4);
        *(f4*)&Ws[kl + 16*i][nl4] = wv;
    }
    __syncthreads();
    const int kg = t >> 6, nl = t & 63;
    h8 hi, lo;
    #pragma unroll
    for (int e8 = 0; e8 < 8; ++e8) {
        float x = Ws[kg*8 + e8][nl] * SCALE_B;
        _Float16 h = (_Float16)x;
        hi[e8] = h;
        lo[e8] = (_Float16)(x - (float)h);
    }
    const int nf  = nfb + (nl >> 4);
    const int l16 = (nl & 15) + 16*kg;
    char* p = Bimg + (size_t)emb*BIMG_EMBED
            + ((size_t)(nh*32 + ks)*2)*8192 + nf*1024 + l16*16;
    *(h8*)p = hi;
    *(h8*)(p + 8192) = lo;
}

// ---------------- activation pre-split: fragment-linear hi/lo f16 image -----
// per embed: [rb(80)][ks(32)][s(2)][m(8)][lane(64)][e(8)] f16 (16KB tiles)
__global__ __launch_bounds__(256) void k_asplit(const float* __restrict__ hist,
    const float* __restrict__ ques, char* __restrict__ Aimg)
{
    const int rb = blockIdx.x, ks = blockIdx.y, z = blockIdx.z;
    const float* X = z ? ques : hist;
    char* dst = Aimg + (size_t)z*AIMG_EMBED + ((size_t)(rb*32 + ks))*16384;
    const int t = threadIdx.x;
    #pragma unroll
    for (int i = 0; i < 2; ++i) {
        const int m   = i*4 + (t >> 6);
        const int row = m*16 + (t & 15);
        const int kg  = (t >> 4) & 3;
        const float* src = X + (size_t)(rb*128 + row)*NK + ks*32 + kg*8;
        f4 a0 = *(const f4*)src;
        f4 a1 = *(const f4*)(src + 4);
        h8 hi, lo;
        #pragma unroll
        for (int j = 0; j < 4; ++j) {
            float x0 = a0[j] * SCALE_A;
            _Float16 h0 = (_Float16)x0;
            hi[j] = h0; lo[j] = (_Float16)(x0 - (float)h0);
            float x1 = a1[j] * SCALE_A;
            _Float16 h1 = (_Float16)x1;
            hi[4+j] = h1; lo[4+j] = (_Float16)(x1 - (float)h1);
        }
        *(h8*)(dst + i*4096 + t*16) = hi;
        *(h8*)(dst + 8192 + i*4096 + t*16) = lo;
    }
}

// ---------------- main path: pure glds + MFMA inner loop --------------------
// Block tile: 128 rows x (64 y-cols + 64 g-cols). 4 waves = 2(row) x 2(col).
__global__ __launch_bounds__(256) void k_embed_mfma2(
    const char* __restrict__ Aimg, const char* __restrict__ Bimg,
    const float* __restrict__ by_h, const float* __restrict__ bg_h,
    const float* __restrict__ by_q, const float* __restrict__ bg_q,
    const float* __restrict__ vv, float* __restrict__ tout)
{
    const int z = blockIdx.z, nt = blockIdx.y, rb = blockIdx.x;
    const float* by = z ? by_q : by_h;
    const float* bg = z ? bg_q : bg_h;
    const float* v  = vv + z*NL;
    float* tptr = tout + (size_t)z*NM;
    const char* At = Aimg + (size_t)z*AIMG_EMBED + ((size_t)rb*32)*16384;
    const char* Bt = Bimg + (size_t)z*BIMG_EMBED + (size_t)nt*32*16384;

    __shared__ char smem[32768];
    char* sA = smem;
    char* sB = smem + 16384;

    const int t = threadIdx.x;
    const int l = t & 63, w = t >> 6;
    const int wr = w >> 1, wc = w & 1;

    f32x4 acc[4][4];
    #pragma unroll
    for (int m = 0; m < 4; ++m)
      #pragma unroll
      for (int n = 0; n < 4; ++n) { f32x4 zz = {0.f,0.f,0.f,0.f}; acc[m][n] = zz; }

    for (int ks = 0; ks < 32; ++ks) {
        const char* ga = At + ks*16384 + w*4096 + l*16;
        const char* gb = Bt + ks*16384 + w*4096 + l*16;
        #pragma unroll
        for (int j = 0; j < 4; ++j) {
            gl_lds16(ga + j*1024, sA + w*4096 + j*1024);
            gl_lds16(gb + j*1024, sB + w*4096 + j*1024);
        }
        __syncthreads();
        h8 av[4][2], bv[4][2];
        #pragma unroll
        for (int m = 0; m < 4; ++m)
          #pragma unroll
          for (int s = 0; s < 2; ++s)
            av[m][s] = *(const h8*)(sA + s*8192 + (wr*4 + m)*1024 + l*16);
        #pragma unroll
        for (int fn = 0; fn < 4; ++fn) {
            const int nf = (fn < 2) ? (wc*2 + fn) : (4 + wc*2 + (fn - 2));
            #pragma unroll
            for (int s = 0; s < 2; ++s)
                bv[fn][s] = *(const h8*)(sB + s*8192 + nf*1024 + l*16);
        }
        #pragma unroll
        for (int m = 0; m < 4; ++m)
          #pragma unroll
          for (int fn = 0; fn < 4; ++fn) {
            acc[m][fn] = __builtin_amdgcn_mfma_f32_16x16x32_f16(av[m][0], bv[fn][0], acc[m][fn], 0, 0, 0);
            acc[m][fn] = __builtin_amdgcn_mfma_f32_16x16x32_f16(av[m][0], bv[fn][1], acc[m][fn], 0, 0, 0);
            acc[m][fn] = __builtin_amdgcn_mfma_f32_16x16x32_f16(av[m][1], bv[fn][0], acc[m][fn], 0, 0, 0);
          }
        __syncthreads();
    }

    const int coll = l & 15, rg = l >> 4;
    #pragma unroll
    for (int m = 0; m < 4; ++m) {
      #pragma unroll
      for (int r = 0; r < 4; ++r) {
        float ps = 0.0f;
        #pragma unroll
        for (int n = 0; n < 2; ++n) {
            const int c = nt*64 + wc*32 + n*16 + coll;
            float y = acc[m][n  ][r]*INV_SCALE + by[c];
            float g = acc[m][n+2][r]*INV_SCALE + bg[c];
            ps += v[c] * (tanhf(y) * (1.0f/(1.0f + expf(-g))));
        }
        ps += __shfl_xor(ps, 1);
        ps += __shfl_xor(ps, 2);
        ps += __shfl_xor(ps, 4);
        ps += __shfl_xor(ps, 8);
        if (coll == 0)
            atomicAdd(&tptr[rb*128 + wr*64 + m*16 + rg*4 + r], ps);
      }
    }
}

// ---------------- middle path: on-the-fly A split (swizzled) + glds B -------
__global__ __launch_bounds__(256) void k_embed_mfma(
    const float* __restrict__ hist, const float* __restrict__ ques,
    const char* __restrict__ Bimg,
    const float* __restrict__ by_h, const float* __restrict__ bg_h,
    const float* __restrict__ by_q, const float* __restrict__ bg_q,
    const float* __restrict__ vv, float* __restrict__ tout)
{
    const int z = blockIdx.z;
    const float* X  = z ? ques : hist;
    const float* by = z ? by_q : by_h;
    const float* bg = z ? bg_q : bg_h;
    const float* v  = vv + z*NL;
    float* tptr = tout + (size_t)z*NM;
    const int nt = blockIdx.y;
    const char* Bt0 = Bimg + (size_t)z*BIMG_EMBED + (size_t)nt*32*16384;
    const int row0 = blockIdx.x * 128;

    __shared__ char smem[32768];
    char* sA = smem;
    char* sB = smem + 16384;

    const int t = threadIdx.x;
    const int l = t & 63, w = t >> 6;
    const int wr = w >> 1, wc = w & 1;

    const int arow = t >> 3;
    const int ak4  = (t & 7) << 2;
    const int akg  = (t & 7) >> 1;
    const int ae0  = (t & 1) << 2;
    const float* Xp = X + (size_t)(row0 + arow)*NK + ak4;
    const int awb = (((arow >> 4) * 1024) + (((arow & 15) + 16*akg) * 16) + ae0*2)
                    ^ (akg << 5);   // XOR-swizzle kills the 4-way write conflict

    f32x4 acc[4][4];
    #pragma unroll
    for (int m = 0; m < 4; ++m)
      #pragma unroll
      for (int n = 0; n < 4; ++n) { f32x4 zz = {0.f,0.f,0.f,0.f}; acc[m][n] = zz; }

    for (int ks = 0; ks < 32; ++ks) {
        const int k0 = ks << 5;
        #pragma unroll
        for (int i = 0; i < 4; ++i) {
            f4 a = *(const f4*)(Xp + k0 + (size_t)i*32*NK);
            h4 hi, lo;
            #pragma unroll
            for (int j = 0; j < 4; ++j) {
                float xs = a[j] * SCALE_A;
                _Float16 h = (_Float16)xs;
                hi[j] = h;
                lo[j] = (_Float16)(xs - (float)h);
            }
            *(h4*)(sA +        awb + i*2048) = hi;
            *(h4*)(sA + 8192 + awb + i*2048) = lo;
        }
        const char* gb = Bt0 + (size_t)ks*16384 + w*4096 + l*16;
        #pragma unroll
        for (int j = 0; j < 4; ++j)
            gl_lds16(gb + j*1024, sB + w*4096 + j*1024);
        __syncthreads();
        h8 av[4][2], bv[4][2];
        const int alsw = (l*16) ^ ((l & 48) << 1);
        #pragma unroll
        for (int m = 0; m < 4; ++m)
          #pragma unroll
          for (int s = 0; s < 2; ++s)
            av[m][s] = *(const h8*)(sA + s*8192 + (wr*4 + m)*1024 + alsw);
        #pragma unroll
        for (int fn = 0; fn < 4; ++fn) {
            const int nf = (fn < 2) ? (wc*2 + fn) : (4 + wc*2 + (fn - 2));
            #pragma unroll
            for (int s = 0; s < 2; ++s)
                bv[fn][s] = *(const h8*)(sB + s*8192 + nf*1024 + l*16);
        }
        #pragma unroll
        for (int m = 0; m < 4; ++m)
          #pragma unroll
          for (int fn = 0; fn < 4; ++fn) {
            acc[m][fn] = __builtin_amdgcn_mfma_f32_16x16x32_f16(av[m][0], bv[fn][0], acc[m][fn], 0, 0, 0);
            acc[m][fn] = __builtin_amdgcn_mfma_f32_16x16x32_f16(av[m][0], bv[fn][1], acc[m][fn], 0, 0, 0);
            acc[m][fn] = __builtin_amdgcn_mfma_f32_16x16x32_f16(av[m][1], bv[fn][0], acc[m][fn], 0, 0, 0);
          }
        __syncthreads();
    }

    const int coll = l & 15, rg = l >> 4;
    #pragma unroll
    for (int m = 0; m < 4; ++m) {
      #pragma unroll
      for (int r = 0; r < 4; ++r) {
        float ps = 0.0f;
        #pragma unroll
        for (int n = 0; n < 2; ++n) {
            const int c = nt*64 + wc*32 + n*16 + coll;
            float y = acc[m][n  ][r]*INV_SCALE + by[c];
            float g = acc[m][n+2][r]*INV_SCALE + bg[c];
            ps += v[c] * (tanhf(y) * (1.0f/(1.0f + expf(-g))));
        }
        ps += __shfl_xor(ps, 1);
        ps += __shfl_xor(ps, 2);
        ps += __shfl_xor(ps, 4);
        ps += __shfl_xor(ps, 8);
        if (coll == 0)
            atomicAdd(&tptr[row0 + wr*64 + m*16 + rg*4 + r], ps);
      }
    }
}

// ---------------- fallback f32 path (verified round 1) ----------------------
__global__ __launch_bounds__(256) void k_embed(const float* __restrict__ X,
    const float* __restrict__ Wy, const float* __restrict__ by,
    const float* __restrict__ Wg, const float* __restrict__ bg,
    const float* __restrict__ v, float* __restrict__ tout)
{
    __shared__ float As[32][68];
    __shared__ float Bys[32][64];
    __shared__ float Bgs[32][64];
    const int tid  = threadIdx.x;
    const int row0 = blockIdx.x * 64;
    const int c0   = blockIdx.y * 64;
    const int tx = tid & 15, ty = tid >> 4;
    float accy[4][4] = {};
    float accg[4][4] = {};
    const int arow = tid >> 3;
    const int ak   = (tid & 7) << 2;
    const int bk   = tid >> 4;
    const int bc   = (tid & 15) << 2;
    const float* Xp0 = X + (size_t)(row0 + arow)*NK + ak;
    const float* Xp1 = Xp0 + (size_t)32*NK;
    for (int k0 = 0; k0 < NK; k0 += 32) {
        f4 a0 = *(const f4*)(Xp0 + k0);
        f4 a1 = *(const f4*)(Xp1 + k0);
        f4 y0 = *(const f4*)&Wy[(size_t)(k0+bk   )*NL + c0 + bc];
        f4 y1 = *(const f4*)&Wy[(size_t)(k0+bk+16)*NL + c0 + bc];
        f4 g0 = *(const f4*)&Wg[(size_t)(k0+bk   )*NL + c0 + bc];
        f4 g1 = *(const f4*)&Wg[(size_t)(k0+bk+16)*NL + c0 + bc];
        #pragma unroll
        for (int j = 0; j < 4; ++j) {
            As[ak+j][arow]      = a0[j];
            As[ak+j][arow + 32] = a1[j];
        }
        *(f4*)&Bys[bk   ][bc] = y0;
        *(f4*)&Bys[bk+16][bc] = y1;
        *(f4*)&Bgs[bk   ][bc] = g0;
        *(f4*)&Bgs[bk+16][bc] = g1;
        __syncthreads();
        #pragma unroll
        for (int kk = 0; kk < 32; ++kk) {
            f4 a   = *(const f4*)&As [kk][ty<<2];
            f4 byv = *(const f4*)&Bys[kk][tx<<2];
            f4 bgv = *(const f4*)&Bgs[kk][tx<<2];
            #pragma unroll
            for (int rr = 0; rr < 4; ++rr)
                #pragma unroll
                for (int cc2 = 0; cc2 < 4; ++cc2) {
                    accy[rr][cc2] = fmaf(a[rr], byv[cc2], accy[rr][cc2]);
                    accg[rr][cc2] = fmaf(a[rr], bgv[cc2], accg[rr][cc2]);
                }
        }
        __syncthreads();
    }
    float rowsum[4] = {0.f, 0.f, 0.f, 0.f};
    #pragma unroll
    for (int rr = 0; rr < 4; ++rr)
        #pragma unroll
        for (int cc2 = 0; cc2 < 4; ++cc2) {
            int c = c0 + (tx<<2) + cc2;
            float xy = accy[rr][cc2] + by[c];
            float xg = accg[rr][cc2] + bg[c];
            float hv = tanhf(xy) * (1.0f / (1.0f + expf(-xg)));
            rowsum[rr] += v[c] * hv;
        }
    float* red = &As[0][0];
    #pragma unroll
    for (int rr = 0; rr < 4; ++rr) red[(ty*4 + rr)*16 + tx] = rowsum[rr];
    __syncthreads();
    if (tid < 64) {
        float s = 0.0f;
        #pragma unroll
        for (int t2 = 0; t2 < 16; ++t2) s += red[tid*16 + t2];
        atomicAdd(&tout[row0 + tid], s);
    }
}

// ---------------- logits -> masked Gumbel argmax -> one-hot -----------------
__global__ __launch_bounds__(256) void k_final(const float* __restrict__ th,
    const float* __restrict__ tq, const float* __restrict__ cc,
    const float* __restrict__ noise, const float* __restrict__ Wa,
    const float* __restrict__ ba, float* __restrict__ out)
{
    int idx = blockIdx.x*256 + threadIdx.x;   // = b*NR + i
    if (idx >= NM) return;
    int b = idx / NR, i = idx % NR;
    float wa0 = Wa[0], wa1 = Wa[1], bav = ba[0], c = cc[0];
    float ti = tq[idx];
    const float EPS = 1e-10f;
    float best = -3.0e38f; int am = 0;
    for (int j = 0; j < NR; ++j) {
        float zz;
        if (j <= i) {
            float n = noise[idx*NR + j];
            float g = -logf(EPS - logf(n + EPS));
            float score = ti + th[b*NR + j] + c;
            zz = score*wa0 + (float)(i - j + 1)*wa1 + bav + g;
        } else {
            zz = -1.0e9f;
        }
        if (zz > best) { best = zz; am = j; }
    }
    #pragma unroll
    for (int j = 0; j < NR; ++j) out[idx*NR + j] = (j == am) ? 1.0f : 0.0f;
}

extern "C" void kernel_launch(void* const* d_in, const int* in_sizes, int n_in,
                              void* d_out, int out_size, void* d_ws, size_t ws_size,
                              hipStream_t stream) {
    (void)in_sizes; (void)n_in; (void)out_size;
    const float* hist  = (const float*)d_in[0];
    const float* ques  = (const float*)d_in[1];
    const float* noise = (const float*)d_in[2];
    const float* Wy_h  = (const float*)d_in[3];
    const float* by_h  = (const float*)d_in[4];
    const float* Wg_h  = (const float*)d_in[5];
    const float* bg_h  = (const float*)d_in[6];
    const float* Wy_q  = (const float*)d_in[7];
    const float* by_q  = (const float*)d_in[8];
    const float* Wg_q  = (const float*)d_in[9];
    const float* bg_q  = (const float*)d_in[10];
    const float* W1    = (const float*)d_in[11];
    const float* b1    = (const float*)d_in[12];
    const float* W2    = (const float*)d_in[13];
    const float* b2    = (const float*)d_in[14];
    const float* Wa    = (const float*)d_in[15];
    const float* ba    = (const float*)d_in[16];
    float* out = (float*)d_out;

    float* ws     = (float*)d_ws;
    float* t_h    = ws;                 // [10240]
    float* t_q    = ws + NM;            // [10240]
    float* v_h    = ws + 2*NM;          // [512]
    float* v_q    = v_h + NL;           // [512]
    float* cconst = v_q + NL;           // [1]

    hipMemsetAsync(t_h, 0, 2*NM*sizeof(float), stream);
    k_vcalc2<<<1025, 256, 0, stream>>>(W1, b1, W2, b2, v_h, v_q, cconst);

    if (ws_size >= WS_NEED2) {
        char* Bimg = (char*)d_ws + BIMG_OFF;
        char* Aimg = (char*)d_ws + AIMG_OFF;
        k_wsplit<<<dim3(8, 32, 4), 256, 0, stream>>>(Wy_h, Wg_h, Wy_q, Wg_q, Bimg);
        k_asplit<<<dim3(80, 32, 2), 256, 0, stream>>>(hist, ques, Aimg);
        k_embed_mfma2<<<dim3(80, 8, 2), 256, 0, stream>>>(Aimg, Bimg,
            by_h, bg_h, by_q, bg_q, v_h, t_h);
    } else if (ws_size >= WS_NEED) {
        char* Bimg = (char*)d_ws + BIMG_OFF;
        k_wsplit<<<dim3(8, 32, 4), 256, 0, stream>>>(Wy_h, Wg_h, Wy_q, Wg_q, Bimg);
        k_embed_mfma<<<dim3(80, 8, 2), 256, 0, stream>>>(hist, ques, Bimg,
            by_h, bg_h, by_q, bg_q, v_h, t_h);
    } else {
        dim3 g(NM/64, NL/64);
        k_embed<<<g, 256, 0, stream>>>(hist, Wy_h, by_h, Wg_h, bg_h, v_h, t_h);
        k_embed<<<g, 256, 0, stream>>>(ques, Wy_q, by_q, Wg_q, bg_q, v_q, t_q);
    }
    k_final<<<(NM + 255)/256, 256, 0, stream>>>(t_h, t_q, cconst, noise, Wa, ba, out);
}

// Round 5
// 277.717 us; speedup vs baseline: 2.5023x; 1.1320x over previous
//
#include <hip/hip_runtime.h>
#include <math.h>

typedef float f4 __attribute__((ext_vector_type(4)));
typedef float f32x4 __attribute__((ext_vector_type(4)));
typedef _Float16 h4 __attribute__((ext_vector_type(4)));
typedef _Float16 h8 __attribute__((ext_vector_type(8)));

#define NB 1024
#define NR 10
#define NL 512
#define NM (NB*NR)      // 10240 rows
#define NK (2*NL)       // 1024  K-dim

#define BIMG_OFF   131072ull
#define BIMG_EMBED 4194304ull                       // 4 MB per embed (B image)
#define AIMG_OFF   (BIMG_OFF + 2ull*BIMG_EMBED)
#define AIMG_EMBED (80ull*32ull*16384ull)           // 40 MB per embed (A image)
#define WS_NEED2   (AIMG_OFF + 2ull*AIMG_EMBED)     // ~92.4 MB (full path)

#define SCALE_A 16.0f
#define SCALE_B 512.0f
#define INV_SCALE (1.0f/8192.0f)

// async global -> LDS, 16B per lane (dest = wave-uniform base + lane*16)
__device__ __forceinline__ void gl_lds16(const void* g, void* s) {
    __builtin_amdgcn_global_load_lds(
        (const __attribute__((address_space(1))) unsigned int*)g,
        (__attribute__((address_space(3))) unsigned int*)s, 16, 0, 0);
}

// ===================== fused prep kernel ====================================
// blocks [0,5120)          : activation split (rb 80, ks 32, z 2)
// blocks [5120,6144)       : weight split     (nh 8, ks 32, mi 4)
// blocks [6144,7169)       : vcalc            (o 0..1024)
// blocks [7169,7189)       : zero t_h/t_q     (20 blocks x 1024 floats)
__global__ __launch_bounds__(256) void k_prep(
    const float* __restrict__ hist, const float* __restrict__ ques,
    const float* __restrict__ Wy_h, const float* __restrict__ Wg_h,
    const float* __restrict__ Wy_q, const float* __restrict__ Wg_q,
    const float* __restrict__ W1, const float* __restrict__ b1,
    const float* __restrict__ W2, const float* __restrict__ b2,
    char* __restrict__ Aimg, char* __restrict__ Bimg,
    float* __restrict__ vh, float* __restrict__ vq, float* __restrict__ cc,
    float* __restrict__ tzero)
{
    __shared__ float Ws[32][68];
    __shared__ float red[4];
    const int bid = blockIdx.x;
    const int t = threadIdx.x;

    if (bid < 5120) {
        // ---- activation pre-split: [rb][ks][s(2)][m(8)][lane(64)][e(8)] f16
        const int rb = bid % 80, ks = (bid / 80) % 32, z = bid / 2560;
        const float* X = z ? ques : hist;
        char* dst = Aimg + (size_t)z*AIMG_EMBED + ((size_t)(rb*32 + ks))*16384;
        #pragma unroll
        for (int i = 0; i < 2; ++i) {
            const int m   = i*4 + (t >> 6);
            const int row = m*16 + (t & 15);
            const int kg  = (t >> 4) & 3;
            const float* src = X + (size_t)(rb*128 + row)*NK + ks*32 + kg*8;
            f4 a0 = *(const f4*)src;
            f4 a1 = *(const f4*)(src + 4);
            h8 hi, lo;
            #pragma unroll
            for (int j = 0; j < 4; ++j) {
                float x0 = a0[j] * SCALE_A;
                _Float16 h0 = (_Float16)x0;
                hi[j] = h0; lo[j] = (_Float16)(x0 - (float)h0);
                float x1 = a1[j] * SCALE_A;
                _Float16 h1 = (_Float16)x1;
                hi[4+j] = h1; lo[4+j] = (_Float16)(x1 - (float)h1);
            }
            *(h8*)(dst + i*4096 + t*16) = hi;
            *(h8*)(dst + 8192 + i*4096 + t*16) = lo;
        }
    } else if (bid < 6144) {
        // ---- weight pre-split: [nt][ks][s(2)][nf(8)][lane(64)][e(8)] f16
        const int wb = bid - 5120;
        const int nh = wb % 8, ks = (wb / 8) % 32, mi = wb / 256;
        const float* W = (mi==0) ? Wy_h : (mi==1) ? Wg_h : (mi==2) ? Wy_q : Wg_q;
        const int emb = mi >> 1, nfb = (mi & 1) * 4;
        const int kl = t >> 4, nl4 = (t & 15) * 4;
        #pragma unroll
        for (int i = 0; i < 2; ++i) {
            f4 wv = *(const f4*)(W + (size_t)(ks*32 + kl + 16*i)*NL + nh*64 + nl4);
            *(f4*)&Ws[kl + 16*i][nl4] = wv;
        }
        __syncthreads();
        const int kg = t >> 6, nl = t & 63;
        h8 hi, lo;
        #pragma unroll
        for (int e8 = 0; e8 < 8; ++e8) {
            float x = Ws[kg*8 + e8][nl] * SCALE_B;
            _Float16 h = (_Float16)x;
            hi[e8] = h;
            lo[e8] = (_Float16)(x - (float)h);
        }
        const int nf  = nfb + (nl >> 4);
        const int l16 = (nl & 15) + 16*kg;
        char* p = Bimg + (size_t)emb*BIMG_EMBED
                + ((size_t)(nh*32 + ks)*2)*8192 + nf*1024 + l16*16;
        *(h8*)p = hi;
        *(h8*)(p + 8192) = lo;
    } else if (bid < 7169) {
        // ---- v_h = W1[:L]@W2, v_q = W1[L:]@W2, c = b1.W2 + b2
        const int o = bid - 6144;
        const float* row = (o < 1024) ? (W1 + (size_t)o*NL) : b1;
        float s = fmaf(row[t], W2[t], row[t+256]*W2[t+256]);
        #pragma unroll
        for (int d = 1; d < 64; d <<= 1) s += __shfl_xor(s, d);
        if ((t & 63) == 0) red[t >> 6] = s;
        __syncthreads();
        if (t == 0) {
            float tot = red[0] + red[1] + red[2] + red[3];
            if (o < 512) vh[o] = tot;
            else if (o < 1024) vq[o-512] = tot;
            else cc[0] = tot + b2[0];
        }
    } else {
        // ---- zero t_h/t_q (2*NM = 20480 floats, 20 blocks x 1024)
        const int zb = bid - 7169;
        f4 zz = {0.f, 0.f, 0.f, 0.f};
        *(f4*)(tzero + (size_t)zb*1024 + t*4) = zz;
    }
}

// ===================== main embed: 2-deep pipelined MFMA ====================
// Block tile: 128 rows x (64 y-cols + 64 g-cols). 4 waves = 2(row) x 2(col).
// Double-buffered LDS, counted vmcnt, raw barriers, setprio around MFMA.
__global__ __launch_bounds__(256, 2) void k_embed_mfma3(
    const char* __restrict__ Aimg, const char* __restrict__ Bimg,
    const float* __restrict__ by_h, const float* __restrict__ bg_h,
    const float* __restrict__ by_q, const float* __restrict__ bg_q,
    const float* __restrict__ vv, float* __restrict__ tout)
{
    const int z = blockIdx.z, nt = blockIdx.y, rb = blockIdx.x;
    const float* by = z ? by_q : by_h;
    const float* bg = z ? bg_q : bg_h;
    const float* v  = vv + z*NL;
    float* tptr = tout + (size_t)z*NM;
    const char* At = Aimg + (size_t)z*AIMG_EMBED + ((size_t)rb*32)*16384;
    const char* Bt = Bimg + (size_t)z*BIMG_EMBED + (size_t)nt*32*16384;

    __shared__ char smem[65536];          // 2 buffers x (16K A + 16K B)

    const int t = threadIdx.x;
    const int l = t & 63, w = t >> 6;
    const int wr = w >> 1, wc = w & 1;

    f32x4 acc[4][4];
    #pragma unroll
    for (int m = 0; m < 4; ++m)
      #pragma unroll
      for (int n = 0; n < 4; ++n) { f32x4 zz = {0.f,0.f,0.f,0.f}; acc[m][n] = zz; }

    // stage one 32-k step (16KB A + 16KB B) into buffer b; 8 gl_lds per wave
    auto stage = [&](int b, int ksrc) {
        const char* ga = At + (size_t)ksrc*16384 + w*4096 + l*16;
        const char* gb = Bt + (size_t)ksrc*16384 + w*4096 + l*16;
        char* da = smem + b*32768 + w*4096;
        char* db = smem + b*32768 + 16384 + w*4096;
        #pragma unroll
        for (int j = 0; j < 4; ++j) {
            gl_lds16(ga + j*1024, da + j*1024);
            gl_lds16(gb + j*1024, db + j*1024);
        }
    };

    // prologue: fill both buffers, wait for buffer 0 (own 8 oldest loads)
    stage(0, 0);
    stage(1, 1);
    asm volatile("s_waitcnt vmcnt(8)" ::: "memory");
    __builtin_amdgcn_s_barrier();

    #pragma unroll 2
    for (int ks = 0; ks < 32; ++ks) {
        const int cur = ks & 1;
        const char* sA = smem + cur*32768;
        const char* sB = sA + 16384;

        h8 av[4][2], bv[4][2];
        #pragma unroll
        for (int m = 0; m < 4; ++m)
          #pragma unroll
          for (int s = 0; s < 2; ++s)
            av[m][s] = *(const h8*)(sA + s*8192 + (wr*4 + m)*1024 + l*16);
        #pragma unroll
        for (int fn = 0; fn < 4; ++fn) {
            const int nf = (fn < 2) ? (wc*2 + fn) : (4 + wc*2 + (fn - 2));
            #pragma unroll
            for (int s = 0; s < 2; ++s)
                bv[fn][s] = *(const h8*)(sB + s*8192 + nf*1024 + l*16);
        }
        // my frag reads complete -> barrier -> safe to overwrite cur buffer
        asm volatile("s_waitcnt lgkmcnt(0)" ::: "memory");
        __builtin_amdgcn_sched_barrier(0);
        __builtin_amdgcn_s_barrier();
        if (ks + 2 < 32) stage(cur, ks + 2);

        __builtin_amdgcn_s_setprio(1);
        #pragma unroll
        for (int m = 0; m < 4; ++m)
          #pragma unroll
          for (int fn = 0; fn < 4; ++fn) {
            acc[m][fn] = __builtin_amdgcn_mfma_f32_16x16x32_f16(av[m][0], bv[fn][0], acc[m][fn], 0, 0, 0);
            acc[m][fn] = __builtin_amdgcn_mfma_f32_16x16x32_f16(av[m][0], bv[fn][1], acc[m][fn], 0, 0, 0);
            acc[m][fn] = __builtin_amdgcn_mfma_f32_16x16x32_f16(av[m][1], bv[fn][0], acc[m][fn], 0, 0, 0);
          }
        __builtin_amdgcn_s_setprio(0);

        // counted wait: next buffer's 8 loads (oldest outstanding) complete
        if (ks < 30)       asm volatile("s_waitcnt vmcnt(8)" ::: "memory");
        else if (ks == 30) asm volatile("s_waitcnt vmcnt(0)" ::: "memory");
        if (ks < 31) __builtin_amdgcn_s_barrier();
    }

    // ---- epilogue: unscale, bias, tanh*sigmoid, dot v, row-reduce, atomic
    const int coll = l & 15, rg = l >> 4;
    #pragma unroll
    for (int m = 0; m < 4; ++m) {
      #pragma unroll
      for (int r = 0; r < 4; ++r) {
        float ps = 0.0f;
        #pragma unroll
        for (int n = 0; n < 2; ++n) {
            const int c = nt*64 + wc*32 + n*16 + coll;
            float y = acc[m][n  ][r]*INV_SCALE + by[c];
            float g = acc[m][n+2][r]*INV_SCALE + bg[c];
            ps += v[c] * (tanhf(y) * (1.0f/(1.0f + expf(-g))));
        }
        ps += __shfl_xor(ps, 1);
        ps += __shfl_xor(ps, 2);
        ps += __shfl_xor(ps, 4);
        ps += __shfl_xor(ps, 8);
        if (coll == 0)
            atomicAdd(&tptr[rb*128 + wr*64 + m*16 + rg*4 + r], ps);
      }
    }
}

// ---------------- fallback f32 path (verified round 1) ----------------------
__global__ __launch_bounds__(256) void k_vcalc2(const float* __restrict__ W1,
    const float* __restrict__ b1, const float* __restrict__ W2,
    const float* __restrict__ b2, float* __restrict__ vh,
    float* __restrict__ vq, float* __restrict__ cc)
{
    const int o = blockIdx.x;
    const float* row = (o < 1024) ? (W1 + (size_t)o*NL) : b1;
    const int t = threadIdx.x;
    float s = fmaf(row[t], W2[t], row[t+256]*W2[t+256]);
    #pragma unroll
    for (int d = 1; d < 64; d <<= 1) s += __shfl_xor(s, d);
    __shared__ float red[4];
    if ((t & 63) == 0) red[t >> 6] = s;
    __syncthreads();
    if (t == 0) {
        float tot = red[0] + red[1] + red[2] + red[3];
        if (o < 512) vh[o] = tot;
        else if (o < 1024) vq[o-512] = tot;
        else cc[0] = tot + b2[0];
    }
}

__global__ __launch_bounds__(256) void k_embed(const float* __restrict__ X,
    const float* __restrict__ Wy, const float* __restrict__ by,
    const float* __restrict__ Wg, const float* __restrict__ bg,
    const float* __restrict__ v, float* __restrict__ tout)
{
    __shared__ float As[32][68];
    __shared__ float Bys[32][64];
    __shared__ float Bgs[32][64];
    const int tid  = threadIdx.x;
    const int row0 = blockIdx.x * 64;
    const int c0   = blockIdx.y * 64;
    const int tx = tid & 15, ty = tid >> 4;
    float accy[4][4] = {};
    float accg[4][4] = {};
    const int arow = tid >> 3;
    const int ak   = (tid & 7) << 2;
    const int bk   = tid >> 4;
    const int bc   = (tid & 15) << 2;
    const float* Xp0 = X + (size_t)(row0 + arow)*NK + ak;
    const float* Xp1 = Xp0 + (size_t)32*NK;
    for (int k0 = 0; k0 < NK; k0 += 32) {
        f4 a0 = *(const f4*)(Xp0 + k0);
        f4 a1 = *(const f4*)(Xp1 + k0);
        f4 y0 = *(const f4*)&Wy[(size_t)(k0+bk   )*NL + c0 + bc];
        f4 y1 = *(const f4*)&Wy[(size_t)(k0+bk+16)*NL + c0 + bc];
        f4 g0 = *(const f4*)&Wg[(size_t)(k0+bk   )*NL + c0 + bc];
        f4 g1 = *(const f4*)&Wg[(size_t)(k0+bk+16)*NL + c0 + bc];
        #pragma unroll
        for (int j = 0; j < 4; ++j) {
            As[ak+j][arow]      = a0[j];
            As[ak+j][arow + 32] = a1[j];
        }
        *(f4*)&Bys[bk   ][bc] = y0;
        *(f4*)&Bys[bk+16][bc] = y1;
        *(f4*)&Bgs[bk   ][bc] = g0;
        *(f4*)&Bgs[bk+16][bc] = g1;
        __syncthreads();
        #pragma unroll
        for (int kk = 0; kk < 32; ++kk) {
            f4 a   = *(const f4*)&As [kk][ty<<2];
            f4 byv = *(const f4*)&Bys[kk][tx<<2];
            f4 bgv = *(const f4*)&Bgs[kk][tx<<2];
            #pragma unroll
            for (int rr = 0; rr < 4; ++rr)
                #pragma unroll
                for (int cc2 = 0; cc2 < 4; ++cc2) {
                    accy[rr][cc2] = fmaf(a[rr], byv[cc2], accy[rr][cc2]);
                    accg[rr][cc2] = fmaf(a[rr], bgv[cc2], accg[rr][cc2]);
                }
        }
        __syncthreads();
    }
    float rowsum[4] = {0.f, 0.f, 0.f, 0.f};
    #pragma unroll
    for (int rr = 0; rr < 4; ++rr)
        #pragma unroll
        for (int cc2 = 0; cc2 < 4; ++cc2) {
            int c = c0 + (tx<<2) + cc2;
            float xy = accy[rr][cc2] + by[c];
            float xg = accg[rr][cc2] + bg[c];
            float hv = tanhf(xy) * (1.0f / (1.0f + expf(-xg)));
            rowsum[rr] += v[c] * hv;
        }
    float* red = &As[0][0];
    #pragma unroll
    for (int rr = 0; rr < 4; ++rr) red[(ty*4 + rr)*16 + tx] = rowsum[rr];
    __syncthreads();
    if (tid < 64) {
        float s = 0.0f;
        #pragma unroll
        for (int t2 = 0; t2 < 16; ++t2) s += red[tid*16 + t2];
        atomicAdd(&tout[row0 + tid], s);
    }
}

// ---------------- logits -> masked Gumbel argmax -> one-hot -----------------
__global__ __launch_bounds__(256) void k_final(const float* __restrict__ th,
    const float* __restrict__ tq, const float* __restrict__ cc,
    const float* __restrict__ noise, const float* __restrict__ Wa,
    const float* __restrict__ ba, float* __restrict__ out)
{
    int idx = blockIdx.x*256 + threadIdx.x;   // = b*NR + i
    if (idx >= NM) return;
    int b = idx / NR, i = idx % NR;
    float wa0 = Wa[0], wa1 = Wa[1], bav = ba[0], c = cc[0];
    float ti = tq[idx];
    const float EPS = 1e-10f;
    float best = -3.0e38f; int am = 0;
    for (int j = 0; j < NR; ++j) {
        float zz;
        if (j <= i) {
            float n = noise[idx*NR + j];
            float g = -logf(EPS - logf(n + EPS));
            float score = ti + th[b*NR + j] + c;
            zz = score*wa0 + (float)(i - j + 1)*wa1 + bav + g;
        } else {
            zz = -1.0e9f;
        }
        if (zz > best) { best = zz; am = j; }
    }
    #pragma unroll
    for (int j = 0; j < NR; ++j) out[idx*NR + j] = (j == am) ? 1.0f : 0.0f;
}

extern "C" void kernel_launch(void* const* d_in, const int* in_sizes, int n_in,
                              void* d_out, int out_size, void* d_ws, size_t ws_size,
                              hipStream_t stream) {
    (void)in_sizes; (void)n_in; (void)out_size;
    const float* hist  = (const float*)d_in[0];
    const float* ques  = (const float*)d_in[1];
    const float* noise = (const float*)d_in[2];
    const float* Wy_h  = (const float*)d_in[3];
    const float* by_h  = (const float*)d_in[4];
    const float* Wg_h  = (const float*)d_in[5];
    const float* bg_h  = (const float*)d_in[6];
    const float* Wy_q  = (const float*)d_in[7];
    const float* by_q  = (const float*)d_in[8];
    const float* Wg_q  = (const float*)d_in[9];
    const float* bg_q  = (const float*)d_in[10];
    const float* W1    = (const float*)d_in[11];
    const float* b1    = (const float*)d_in[12];
    const float* W2    = (const float*)d_in[13];
    const float* b2    = (const float*)d_in[14];
    const float* Wa    = (const float*)d_in[15];
    const float* ba    = (const float*)d_in[16];
    float* out = (float*)d_out;

    float* ws     = (float*)d_ws;
    float* t_h    = ws;                 // [10240]
    float* t_q    = ws + NM;            // [10240]
    float* v_h    = ws + 2*NM;          // [512]
    float* v_q    = v_h + NL;           // [512]
    float* cconst = v_q + NL;           // [1]

    if (ws_size >= WS_NEED2) {
        char* Bimg = (char*)d_ws + BIMG_OFF;
        char* Aimg = (char*)d_ws + AIMG_OFF;
        k_prep<<<7189, 256, 0, stream>>>(hist, ques, Wy_h, Wg_h, Wy_q, Wg_q,
            W1, b1, W2, b2, Aimg, Bimg, v_h, v_q, cconst, t_h);
        k_embed_mfma3<<<dim3(80, 8, 2), 256, 0, stream>>>(Aimg, Bimg,
            by_h, bg_h, by_q, bg_q, v_h, t_h);
    } else {
        hipMemsetAsync(t_h, 0, 2*NM*sizeof(float), stream);
        k_vcalc2<<<1025, 256, 0, stream>>>(W1, b1, W2, b2, v_h, v_q, cconst);
        dim3 g(NM/64, NL/64);
        k_embed<<<g, 256, 0, stream>>>(hist, Wy_h, by_h, Wg_h, bg_h, v_h, t_h);
        k_embed<<<g, 256, 0, stream>>>(ques, Wy_q, by_q, Wg_q, bg_q, v_q, t_q);
    }
    k_final<<<(NM + 255)/256, 256, 0, stream>>>(t_h, t_q, cconst, noise, Wa, ba, out);
}